// Round 13
// baseline (2438.727 us; speedup 1.0000x reference)
//
#include <hip/hip_runtime.h>
#include <hip/hip_bf16.h>

// ---------------------------------------------------------------------------
// PredRNN (patched) — R13: R12 champion + 2x occupancy via 16-px half-row
// blocks. kcellA/kcellB grids (8,32,2) = 512 blocks = 2 blocks/CU (was 256 =
// 1/CU, 1.75 waves/SIMD). Wave tile 64co x 16px (acc[4]); staging strips are
// 18 cols (16 + 2 halo). All arithmetic identical to R12 (2405us).
// ---------------------------------------------------------------------------

typedef __bf16 bf16x8 __attribute__((ext_vector_type(8)));
typedef float f32x4 __attribute__((ext_vector_type(4)));

namespace {
constexpr int  T     = 19;
constexpr int  INLEN = 10;

// workspace offsets (in floats)
constexpr long OFF_XPB   = 0;            // bf16 [8][10][1024][64]
constexpr long OFF_OUTSB = 2621440;      // bf16 [19][8][1024][64]
constexpr long OFF_HB    = 7602176;      // bf16 [4][8][1024][64]
constexpr long OFF_C     = 9699328;      // fp32 [4][8][64][1024]
constexpr long OFF_M     = 11796480;     // fp32 [8][64][1024]
constexpr long OFF_MEMB  = 12320768;     // bf16 2x [8][1024][128] (ping-pong)
constexpr long OFF_OP    = 13369344;     // fp32 [8][64][1024]
constexpr long OFF_WFA   = 13893632;     // bf16 4 x 516096
constexpr long OFF_WFB   = 14925824;     // bf16 4 x 81920
constexpr long OFF_WFD   = 15089664;     // bf16 36864
constexpr long OFF_BA    = 15108096;     // fp32 4 x 448
constexpr long WS_NEEDED_FLOATS = 15109888;
}

__device__ __forceinline__ float sigf(float x)     { return 1.f / (1.f + __expf(-x)); }
__device__ __forceinline__ float tanhfast(float x) { return 2.f / (1.f + __expf(-2.f * x)) - 1.f; }
__device__ __forceinline__ unsigned short f2b(float f) {
  __hip_bfloat16 h = __float2bfloat16(f);
  return __builtin_bit_cast(unsigned short, h);
}
__device__ __forceinline__ f32x4 mfma16(bf16x8 a, bf16x8 b, f32x4 c) {
  return __builtin_amdgcn_mfma_f32_16x16x32_bf16(a, b, c, 0, 0, 0);
}

// ---------------------------------------------------------------------------
// kcellA: grid (8, 32, 2), 448 threads (7 waves). Block = (b, row r0, colhalf z).
// Wave w gate: w0=i w1=f w2=g w3=o (inputs x,h) ; w4=i' w5=f' w6=g' (x,m).
// Wave tile: 64co x 16px (cols z*16..z*16+15 of row r0), acc[4].
// ---------------------------------------------------------------------------
__global__ __launch_bounds__(448) void kcellA(
    const unsigned short* __restrict__ in0, long in0bs,
    const unsigned short* __restrict__ hB,
    const unsigned short* __restrict__ memBprev,
    const unsigned short* __restrict__ wfA,
    const float* __restrict__ bA,
    float* __restrict__ C, float* __restrict__ M,
    unsigned short* __restrict__ memBnext,
    float* __restrict__ op)
{
  __shared__ __align__(16) char smem[32768];
  unsigned short* sIn = (unsigned short*)smem;   // 3 strips x 54 slots x 64ch (20736B)
  float* sEx = (float*)smem;                     // 7 slabs x 1024 fp32 (28672B, reuse)
  unsigned short* sT = (unsigned short*)(smem + 28672);  // 16px x 128ch (4096B)

  const int b = blockIdx.x, r0 = blockIdx.y, z = blockIdx.z, tid = threadIdx.x;
  const unsigned short* base0 = in0 + (long)b * in0bs;
  const unsigned short* base1 = hB + ((long)b << 16);
  const unsigned short* base2 = memBprev + ((long)b << 17);

  // stage 3 input strips: rows r0-1..r0+1, cols z*16-1..z*16+16, 64 ci, swizzled
  for (int s = tid; s < 3 * 432; s += 448) {
    int strip = s / 432, rem = s - strip * 432;
    int slot = rem >> 3, cg = rem & 7;
    int rr = slot / 18, cl = slot - rr * 18;
    int gr = r0 - 1 + rr, gc = z * 16 - 1 + cl;
    uint4 v = make_uint4(0u, 0u, 0u, 0u);
    if ((unsigned)gr < 32u && (unsigned)gc < 32u) {
      if (strip == 0)      v = *(const uint4*)(base0 + ((long)(gr * 32 + gc) << 6) + cg * 8);
      else if (strip == 1) v = *(const uint4*)(base1 + ((long)(gr * 32 + gc) << 6) + cg * 8);
      else                 v = *(const uint4*)(base2 + ((long)(gr * 32 + gc) << 7) + 64 + cg * 8);
    }
    *(uint4*)(sIn + strip * 3456 + slot * 64 + ((cg ^ (slot & 7)) * 8)) = v;
  }
  __syncthreads();

  const int w = tid >> 6, lane = tid & 63, q = lane >> 4, n16 = lane & 15;
  f32x4 acc[4];
  #pragma unroll
  for (int i = 0; i < 4; ++i) acc[i] = (f32x4){0.f, 0.f, 0.f, 0.f};

  const unsigned short* sb1 = sIn + ((w < 4) ? 3456 : 6912);
  const unsigned short* wbase = wfA + (long)w * 73728;

  #pragma unroll
  for (int p = 0; p < 2; ++p) {
    const unsigned short* sb = p ? sb1 : sIn;
    #pragma unroll
    for (int tap = 0; tap < 9; ++tap) {
      const int dy = tap / 3, dx = tap - dy * 3;
      #pragma unroll
      for (int cc = 0; cc < 2; ++cc) {
        const unsigned short* wp = wbase + (long)(((p * 9 + tap) * 2 + cc) * 4) * 512 + lane * 8;
        bf16x8 a0 = *(const bf16x8*)(wp);
        bf16x8 a1 = *(const bf16x8*)(wp + 512);
        bf16x8 a2 = *(const bf16x8*)(wp + 1024);
        bf16x8 a3 = *(const bf16x8*)(wp + 1536);
        const int g = cc * 4 + q;
        const int slot = dy * 18 + dx + n16;
        bf16x8 bf0 = *(const bf16x8*)(sb + slot * 64 + ((g ^ (slot & 7)) * 8));
        acc[0] = mfma16(a0, bf0, acc[0]);
        acc[1] = mfma16(a1, bf0, acc[1]);
        acc[2] = mfma16(a2, bf0, acc[2]);
        acc[3] = mfma16(a3, bf0, acc[3]);
      }
    }
  }

  __syncthreads();   // all waves done reading sIn before slab overwrite

  // hoist epilogue C/M loads (independent of sEx) above exchange barriers
  float cPre[3], mPre[3];
  #pragma unroll
  for (int k = 0; k < 3; ++k) {
    const int idx = tid + k * 448;
    if (idx < 1024) {
      const int ch = idx >> 4, pxl = idx & 15;
      const long cmo = ((long)b * 64 + ch) * 1024 + r0 * 32 + z * 16 + pxl;
      cPre[k] = C[cmo];
      mPre[k] = M[cmo];
    }
  }

  #pragma unroll
  for (int i = 0; i < 4; ++i)
    #pragma unroll
    for (int r = 0; r < 4; ++r)
      sEx[w * 1024 + (i * 16 + q * 4 + r) * 16 + n16] = acc[i][r];
  __syncthreads();

  // gate1 epilogue: state update + bf16 tile in LDS (1024 items)
  #pragma unroll
  for (int k = 0; k < 3; ++k) {
    const int idx = tid + k * 448;
    if (idx < 1024) {
      const int ch = idx >> 4, pxl = idx & 15;
      const int pxg = r0 * 32 + z * 16 + pxl;
      float iv = sEx[idx]        + bA[ch];
      float fv = sEx[1024 + idx] + bA[64 + ch];
      float gv = sEx[2048 + idx] + bA[128 + ch];
      float ov = sEx[3072 + idx] + bA[192 + ch];
      float i2 = sEx[4096 + idx] + bA[256 + ch];
      float f2 = sEx[5120 + idx] + bA[320 + ch];
      float g2 = sEx[6144 + idx] + bA[384 + ch];
      const long cmo = ((long)b * 64 + ch) * 1024 + pxg;
      float cn = sigf(fv) * cPre[k] + sigf(iv) * tanhfast(gv);
      float mn = sigf(f2) * mPre[k] + sigf(i2) * tanhfast(g2);
      C[cmo] = cn; M[cmo] = mn; op[cmo] = ov;
      sT[pxl * 128 + (((ch >> 3) ^ (pxl & 7)) * 8) + (ch & 7)] = f2b(cn);
      const int chm = 64 + ch;
      sT[pxl * 128 + (((chm >> 3) ^ (pxl & 7)) * 8) + (chm & 7)] = f2b(mn);
    }
  }
  __syncthreads();

  // coalesced flush: 256 uint4 (16px x 16 ch-groups)
  for (int u = tid; u < 256; u += 448) {
    const int px = u >> 4, cg = u & 15;
    uint4 v = *(const uint4*)(sT + px * 128 + ((cg ^ (px & 7)) * 8));
    *(uint4*)(memBnext + (((long)b * 1024 + r0 * 32 + z * 16 + px) << 7) + cg * 8) = v;
  }
}

// ---------------------------------------------------------------------------
// kcellB: grid (8, 32, 2), 512 threads (8 waves). 40 K-steps split 5/wave;
// wave tile 64co x 16px; LDS reduce; gate2 epilogue.
// ---------------------------------------------------------------------------
__global__ __launch_bounds__(512) void kcellB(
    const unsigned short* __restrict__ memB,
    const unsigned short* __restrict__ wfBl,
    const float* __restrict__ op, const float* __restrict__ bl,
    unsigned short* __restrict__ hBw, unsigned short* __restrict__ outsBt,
    int writeOuts)
{
  __shared__ __align__(16) char smem[38912];
  unsigned short* sIn = (unsigned short*)smem;   // 54 slots x 128 ci (13824B)
  float* sEx = (float*)smem;                     // 9 slabs x 1024 fp32 (36864B, reuse)
  unsigned short* sT = (unsigned short*)(smem + 36864);  // 16px x 64ch (2048B)

  const int b = blockIdx.x, r0 = blockIdx.y, z = blockIdx.z, tid = threadIdx.x;
  const unsigned short* bp = memB + ((long)b << 17);
  for (int s = tid; s < 54 * 16; s += 512) {
    int slot = s >> 4, cg = s & 15;
    int rr = slot / 18, cl = slot - rr * 18;
    int gr = r0 - 1 + rr, gc = z * 16 - 1 + cl;
    uint4 v = make_uint4(0u, 0u, 0u, 0u);
    if ((unsigned)gr < 32u && (unsigned)gc < 32u)
      v = *(const uint4*)(bp + ((long)(gr * 32 + gc) << 7) + cg * 8);
    *(uint4*)(sIn + slot * 128 + ((cg ^ (slot & 7)) * 8)) = v;
  }
  __syncthreads();

  const int w = tid >> 6, lane = tid & 63, q = lane >> 4, n16 = lane & 15;
  f32x4 accO[4], accL[4];
  #pragma unroll
  for (int f = 0; f < 4; ++f) {
    accO[f] = (f32x4){0.f,0.f,0.f,0.f};
    accL[f] = (f32x4){0.f,0.f,0.f,0.f};
  }

  #pragma unroll
  for (int s5 = 0; s5 < 5; ++s5) {
    const int s = w * 5 + s5;
    const bool isL = (s >= 36);
    const int tap = isL ? 4 : (s >> 2);
    const int cc  = isL ? (s - 36) : (s & 3);
    const int dy = tap / 3, dx = tap - dy * 3;
    const unsigned short* wp = wfBl + (long)s * 2048 + lane * 8;
    bf16x8 a0 = *(const bf16x8*)(wp);
    bf16x8 a1 = *(const bf16x8*)(wp + 512);
    bf16x8 a2 = *(const bf16x8*)(wp + 1024);
    bf16x8 a3 = *(const bf16x8*)(wp + 1536);
    const int g = cc * 4 + q;
    const int slot = dy * 18 + dx + n16;
    bf16x8 bf0 = *(const bf16x8*)(sIn + slot * 128 + ((g ^ (slot & 7)) * 8));
    if (isL) {
      accL[0] = mfma16(a0, bf0, accL[0]);
      accL[1] = mfma16(a1, bf0, accL[1]);
      accL[2] = mfma16(a2, bf0, accL[2]);
      accL[3] = mfma16(a3, bf0, accL[3]);
    } else {
      accO[0] = mfma16(a0, bf0, accO[0]);
      accO[1] = mfma16(a1, bf0, accO[1]);
      accO[2] = mfma16(a2, bf0, accO[2]);
      accO[3] = mfma16(a3, bf0, accO[3]);
    }
  }

  // hoist epilogue op loads above exchange barrier
  float oPre[2];
  #pragma unroll
  for (int k = 0; k < 2; ++k) {
    const int idx = tid + k * 512;
    const int ch = idx >> 4, pxl = idx & 15;
    oPre[k] = op[((long)b * 64 + ch) * 1024 + r0 * 32 + z * 16 + pxl];
  }

  __syncthreads();
  #pragma unroll
  for (int i = 0; i < 4; ++i)
    #pragma unroll
    for (int r = 0; r < 4; ++r)
      sEx[w * 1024 + (i * 16 + q * 4 + r) * 16 + n16] = accO[i][r];
  if (w == 7) {
    #pragma unroll
    for (int i = 0; i < 4; ++i)
      #pragma unroll
      for (int r = 0; r < 4; ++r)
        sEx[8192 + (i * 16 + q * 4 + r) * 16 + n16] = accL[i][r];
  }
  __syncthreads();

  #pragma unroll
  for (int k = 0; k < 2; ++k) {
    const int idx = tid + k * 512;
    const int ch = idx >> 4, pxl = idx & 15;
    float o = oPre[k];
    #pragma unroll
    for (int ww = 0; ww < 8; ++ww) o += sEx[ww * 1024 + idx];
    float l = sEx[8192 + idx] + bl[ch];
    sT[pxl * 64 + (((ch >> 3) ^ (pxl & 7)) * 8) + (ch & 7)] = f2b(sigf(o) * tanhfast(l));
  }
  __syncthreads();

  for (int u = tid; u < 128; u += 512) {
    const int px = u >> 3, cg = u & 7;
    uint4 v = *(const uint4*)(sT + px * 64 + ((cg ^ (px & 7)) * 8));
    const long base = (((long)b * 1024 + r0 * 32 + z * 16 + px) << 6) + cg * 8;
    *(uint4*)(hBw + base) = v;
    if (writeOuts) *(uint4*)(outsBt + base) = v;
  }
}

// ---------------------------------------------------------------------------
// Final conv machinery (verbatim R2/R3, proven correct)
// ---------------------------------------------------------------------------
__device__ __forceinline__ void conv3_acc(
    const unsigned short* __restrict__ ip, int ciStride, int ciOff,
    const unsigned short* __restrict__ wf, int ncc, int ccoff,
    unsigned short* sIn, f32x4 (&acc)[4][4])
{
  const int tid = threadIdx.x;
  const int r0  = (int)blockIdx.y * 8;
  for (int s = tid; s < 2720; s += 256) {
    int slot = s >> 3, cg = s & 7;
    int rr = slot / 34, cl = slot - rr * 34;
    int gr = r0 - 1 + rr, gc = cl - 1;
    uint4 v = make_uint4(0u, 0u, 0u, 0u);
    if ((unsigned)gr < 32u && (unsigned)gc < 32u)
      v = *(const uint4*)(ip + (long)(gr * 32 + gc) * ciStride + ciOff + cg * 8);
    *(uint4*)(sIn + slot * 64 + ((cg ^ (slot & 7)) * 8)) = v;
  }
  __syncthreads();
  const int lane = tid & 63, w = tid >> 6;
  const int q = lane >> 4, n16 = lane & 15;
  #pragma unroll
  for (int i = 0; i < 4; ++i)
    #pragma unroll
    for (int j = 0; j < 4; ++j)
      acc[i][j] = (f32x4){0.f, 0.f, 0.f, 0.f};
  #pragma unroll
  for (int tap = 0; tap < 9; ++tap) {
    const int dy = tap / 3, dx = tap - dy * 3;
    #pragma unroll
    for (int cc = 0; cc < 2; ++cc) {
      const unsigned short* wp = wf + (long)(tap * ncc + ccoff + cc) * 2048 + lane * 8;
      bf16x8 a0 = *(const bf16x8*)(wp);
      bf16x8 a1 = *(const bf16x8*)(wp + 512);
      bf16x8 a2 = *(const bf16x8*)(wp + 1024);
      bf16x8 a3 = *(const bf16x8*)(wp + 1536);
      const int cs = cc * 4 + q;
      bf16x8 bfr[4];
      #pragma unroll
      for (int pf = 0; pf < 4; ++pf) {
        int slot = (w * 2 + (pf >> 1) + dy) * 34 + (pf & 1) * 16 + dx + n16;
        bfr[pf] = *(const bf16x8*)(sIn + slot * 64 + ((cs ^ (slot & 7)) * 8));
      }
      #pragma unroll
      for (int j = 0; j < 4; ++j) {
        acc[0][j] = mfma16(a0, bfr[j], acc[0][j]);
        acc[1][j] = mfma16(a1, bfr[j], acc[1][j]);
        acc[2][j] = mfma16(a2, bfr[j], acc[2][j]);
        acc[3][j] = mfma16(a3, bfr[j], acc[3][j]);
      }
    }
  }
}

__global__ __launch_bounds__(256) void kconv_final(
    const unsigned short* __restrict__ outsB,
    const unsigned short* __restrict__ wdf, const float* __restrict__ bd,
    float* __restrict__ dout)
{
  __shared__ __align__(16) unsigned short sIn[21760];
  const int img = blockIdx.x;
  const int b = img / 19, t = img - b * 19;
  f32x4 acc[4][4];
  conv3_acc(outsB + ((long)t * 8 + b) * 65536, 64, 0, wdf, 2, 0, sIn, acc);
  const int tid = threadIdx.x;
  const int lane = tid & 63, w = tid >> 6;
  const int q = lane >> 4, n16 = lane & 15;
  const int r0 = (int)blockIdx.y * 8;
  float* ob = dout + (long)img * 65536;
  #pragma unroll
  for (int i = 0; i < 4; ++i) {
    #pragma unroll
    for (int r = 0; r < 4; ++r) {
      const int co = i * 16 + q * 4 + r;
      const float bv = bd[co];
      #pragma unroll
      for (int j = 0; j < 4; ++j) {
        int row = r0 + w * 2 + (j >> 1);
        int col = (j & 1) * 16 + n16;
        ob[((co >> 3) * 32 + row) * 256 + (co & 7) * 32 + col] = sigf(acc[i][j][r] + bv);
      }
    }
  }
}

// patch division -> bf16 channels-last [b*10+t][1024][64]; grid (80, 32)
__global__ __launch_bounds__(256) void kpatch(const float* __restrict__ x,
                                              unsigned short* __restrict__ xpB)
{
  __shared__ __align__(16) unsigned short sT[2048];
  const int img = blockIdx.x, p = blockIdx.y, tid = threadIdx.x;
  const float* xi = x + (long)img * 65536;
  unsigned short* xo = xpB + (long)img * 65536;
  int ch = tid >> 2, q0 = (tid & 3) * 8;
  const float* s = xi + ((ch >> 3) * 32 + p) * 256 + (ch & 7) * 32 + q0;
  float4 v0 = *(const float4*)s, v1 = *(const float4*)(s + 4);
  float vv[8] = {v0.x, v0.y, v0.z, v0.w, v1.x, v1.y, v1.z, v1.w};
  #pragma unroll
  for (int k = 0; k < 8; ++k) {
    int qq = q0 + k;
    sT[qq * 64 + (((ch >> 3) ^ (qq & 7)) * 8) + (ch & 7)] = f2b(vv[k]);
  }
  __syncthreads();
  int qr = tid >> 3, cg = tid & 7;
  uint4 v = *(const uint4*)(sT + qr * 64 + ((cg ^ (qr & 7)) * 8));
  *(uint4*)(xo + (long)(p * 32 + qr) * 64 + cg * 8) = v;
}

// weight fragment packer (used for Wd only)
__global__ __launch_bounds__(256) void kprepw(const float* __restrict__ src,
                                              unsigned short* __restrict__ dst,
                                              int Cout, int Cin, int KK)
{
  long n = (long)Cout * Cin * KK;
  long idx = (long)blockIdx.x * 256 + threadIdx.x;
  if (idx >= n) return;
  int ncc = Cin >> 5;
  long tmp = idx >> 3; int e = (int)(idx & 7);
  int lane = (int)(tmp & 63); tmp >>= 6;
  int cf = (int)(tmp & 3); tmp >>= 2;
  int cc = (int)(tmp % ncc); tmp /= ncc;
  int tap = (int)(tmp % KK); int chunk = (int)(tmp / KK);
  int co = chunk * 64 + cf * 16 + (lane & 15);
  int ci = cc * 32 + (lane >> 4) * 8 + e;
  dst[idx] = f2b(src[((long)co * Cin + ci) * KK + tap]);
}

// pack fused stage-1 weights (R3 layout): [l][w][p][tap][cc][frag][lane][8]
__global__ __launch_bounds__(256) void kpackA(
    const float* __restrict__ Wx, const float* __restrict__ Wh,
    const float* __restrict__ Wm, unsigned short* __restrict__ wfA)
{
  long idx = (long)blockIdx.x * 256 + threadIdx.x;
  if (idx >= 2064384) return;
  int e = (int)(idx & 7);
  long t = idx >> 3;
  int lane = (int)(t & 63); t >>= 6;
  int frag = (int)(t & 3);  t >>= 2;
  int cc   = (int)(t & 1);  t >>= 1;
  int tap  = (int)(t % 9);  t /= 9;
  int p    = (int)(t & 1);  t >>= 1;
  int w    = (int)(t % 7);
  int l    = (int)(t / 7);
  int co = frag * 16 + (lane & 15);
  int ci = cc * 32 + (lane >> 4) * 8 + e;
  const float* src; int row;
  if (w < 4) {
    if (p == 0) { src = Wx + (long)l * 258048; row = (w == 3 ? 384 : w * 64) + co; }
    else        { src = Wh + (long)l * 147456; row = (w == 3 ? 192 : w * 64) + co; }
  } else {
    if (p == 0) { src = Wx + (long)l * 258048; row = 192 + (w - 4) * 64 + co; }
    else        { src = Wm + (long)l * 110592; row = (w - 4) * 64 + co; }
  }
  wfA[idx] = f2b(src[((long)row * 64 + ci) * 9 + tap]);
}

// pack convO/convL step-ordered weights (R3 layout): [l][s 0..39][frag][lane][8]
__global__ __launch_bounds__(256) void kpackB(
    const float* __restrict__ Wo, const float* __restrict__ Wl,
    unsigned short* __restrict__ wfB)
{
  long idx = (long)blockIdx.x * 256 + threadIdx.x;
  if (idx >= 327680) return;
  int e = (int)(idx & 7);
  long t = idx >> 3;
  int lane = (int)(t & 63); t >>= 6;
  int frag = (int)(t & 3);  t >>= 2;
  int s    = (int)(t % 40);
  int l    = (int)(t / 40);
  int co = frag * 16 + (lane & 15);
  float v;
  if (s < 36) {
    int tap = s >> 2, cc = s & 3;
    int ci = cc * 32 + (lane >> 4) * 8 + e;
    v = Wo[(long)l * 73728 + ((long)co * 128 + ci) * 9 + tap];
  } else {
    int cc = s - 36;
    int ci = cc * 32 + (lane >> 4) * 8 + e;
    v = Wl[(long)l * 8192 + (long)co * 128 + ci];
  }
  wfB[idx] = f2b(v);
}

// pre-summed gate biases: [l][slot i,f,g,o(+bo),i2,f2,g2][64]
__global__ __launch_bounds__(256) void kpackbA(
    const float* __restrict__ bx, const float* __restrict__ bh,
    const float* __restrict__ bm, const float* __restrict__ bo,
    float* __restrict__ bA)
{
  int idx = blockIdx.x * 256 + threadIdx.x;
  if (idx >= 1792) return;
  int ch = idx & 63, w = (idx >> 6) % 7, l = (idx >> 6) / 7;
  const float* bxl = bx + l * 448;
  const float* bhl = bh + l * 256;
  const float* bml = bm + l * 192;
  const float* bol = bo + l * 64;
  float v;
  if (w < 3)       v = bxl[w * 64 + ch] + bhl[w * 64 + ch];
  else if (w == 3) v = bxl[384 + ch] + bhl[192 + ch] + bol[ch];
  else             v = bxl[192 + (w - 4) * 64 + ch] + bml[(w - 4) * 64 + ch];
  bA[idx] = v;
}

extern "C" void kernel_launch(void* const* d_in, const int* in_sizes, int n_in,
                              void* d_out, int out_size, void* d_ws, size_t ws_size,
                              hipStream_t stream)
{
  (void)in_sizes; (void)n_in; (void)out_size;
  if (ws_size < WS_NEEDED_FLOATS * sizeof(float)) return;

  const float* x  = (const float*)d_in[0];
  const float* Wx = (const float*)d_in[3];
  const float* bx = (const float*)d_in[4];
  const float* Wh = (const float*)d_in[5];
  const float* bh = (const float*)d_in[6];
  const float* Wm = (const float*)d_in[7];
  const float* bm = (const float*)d_in[8];
  const float* Wo = (const float*)d_in[9];
  const float* bo = (const float*)d_in[10];
  const float* Wl = (const float*)d_in[11];
  const float* bl = (const float*)d_in[12];
  const float* Wd = (const float*)d_in[13];
  const float* bd = (const float*)d_in[14];
  float* ws  = (float*)d_ws;
  float* out = (float*)d_out;

  unsigned short* xpB   = (unsigned short*)(ws + OFF_XPB);
  unsigned short* outsB = (unsigned short*)(ws + OFF_OUTSB);
  unsigned short* hB    = (unsigned short*)(ws + OFF_HB);
  float*          C     = ws + OFF_C;
  float*          M     = ws + OFF_M;
  unsigned short* memB0 = (unsigned short*)(ws + OFF_MEMB);
  unsigned short* memB1 = memB0 + 1048576;
  float*          OP    = ws + OFF_OP;
  unsigned short* wfA   = (unsigned short*)(ws + OFF_WFA);
  unsigned short* wfB   = (unsigned short*)(ws + OFF_WFB);
  unsigned short* wfD   = (unsigned short*)(ws + OFF_WFD);
  float*          bA    = ws + OFF_BA;

  kpackA<<<dim3(8064), 256, 0, stream>>>(Wx, Wh, Wm, wfA);
  kpackB<<<dim3(1280), 256, 0, stream>>>(Wo, Wl, wfB);
  kpackbA<<<dim3(7), 256, 0, stream>>>(bx, bh, bm, bo, bA);
  kprepw<<<dim3(144), 256, 0, stream>>>(Wd, wfD, 64, 64, 9);
  kpatch<<<dim3(80, 32), 256, 0, stream>>>(x, xpB);
  // zero hB, C, M, memB(2x), OP (contiguous region)
  hipMemsetAsync(ws + OFF_HB, 0, (OFF_WFA - OFF_HB) * sizeof(float), stream);

  for (int t = 0; t < T; ++t) {
    for (int l = 0; l < 4; ++l) {
      const int cell = t * 4 + l;
      const unsigned short* in0; long ibs;
      if (l == 0) {
        if (t < INLEN) { in0 = xpB + (long)t * 65536; ibs = 655360; }
        else           { in0 = outsB + (long)(t - 1) * 524288; ibs = 65536; }
      } else {
        in0 = hB + (long)(l - 1) * 524288; ibs = 65536;
      }
      const unsigned short* mprev = (cell & 1) ? memB1 : memB0;
      unsigned short*       mnext = (cell & 1) ? memB0 : memB1;
      kcellA<<<dim3(8, 32, 2), 448, 0, stream>>>(
          in0, ibs, hB + (long)l * 524288, mprev,
          wfA + (long)l * 516096, bA + l * 448,
          C + (long)l * 524288, M, mnext, OP);
      kcellB<<<dim3(8, 32, 2), 512, 0, stream>>>(
          mnext, wfB + (long)l * 81920, OP, bl + l * 64,
          hB + (long)l * 524288, outsB + (long)t * 524288, (l == 3) ? 1 : 0);
    }
  }
  kconv_final<<<dim3(152, 4), 256, 0, stream>>>(outsB, wfD, bd, out);
}

// Round 14
// 2403.352 us; speedup vs baseline: 1.0147x; 1.0147x over previous
//
#include <hip/hip_runtime.h>
#include <hip/hip_bf16.h>

// ---------------------------------------------------------------------------
// PredRNN (patched) — R14: restore R12 champion (2405us).
// R13's half-row split (2x waves/CU) was neutral-negative: kcellA is NOT
// occupancy-bound (14 waves/CU == 7 waves/CU perf), weight BW not binding
// (R6), staging not binding (R10). Binding constraint: serial 76-cell chain
// x per-dispatch time; launch-boundary ordering beats all measured
// alternatives (grid barrier R5, flag sync R7, halo recompute R8).
// Structure: per cell kcellA (7-wave stage-1 gate GEMMs + gate1, coalesced
// bf16 stores, hoisted C/M loads) + kcellB (convO/convL K-split + gate2).
// ---------------------------------------------------------------------------

typedef __bf16 bf16x8 __attribute__((ext_vector_type(8)));
typedef float f32x4 __attribute__((ext_vector_type(4)));

namespace {
constexpr int  T     = 19;
constexpr int  INLEN = 10;

// workspace offsets (in floats)
constexpr long OFF_XPB   = 0;            // bf16 [8][10][1024][64]
constexpr long OFF_OUTSB = 2621440;      // bf16 [19][8][1024][64]
constexpr long OFF_HB    = 7602176;      // bf16 [4][8][1024][64]
constexpr long OFF_C     = 9699328;      // fp32 [4][8][64][1024]
constexpr long OFF_M     = 11796480;     // fp32 [8][64][1024]
constexpr long OFF_MEMB  = 12320768;     // bf16 2x [8][1024][128] (ping-pong)
constexpr long OFF_OP    = 13369344;     // fp32 [8][64][1024]
constexpr long OFF_WFA   = 13893632;     // bf16 4 x 516096
constexpr long OFF_WFB   = 14925824;     // bf16 4 x 81920
constexpr long OFF_WFD   = 15089664;     // bf16 36864
constexpr long OFF_BA    = 15108096;     // fp32 4 x 448
constexpr long WS_NEEDED_FLOATS = 15109888;
}

__device__ __forceinline__ float sigf(float x)     { return 1.f / (1.f + __expf(-x)); }
__device__ __forceinline__ float tanhfast(float x) { return 2.f / (1.f + __expf(-2.f * x)) - 1.f; }
__device__ __forceinline__ unsigned short f2b(float f) {
  __hip_bfloat16 h = __float2bfloat16(f);
  return __builtin_bit_cast(unsigned short, h);
}
__device__ __forceinline__ f32x4 mfma16(bf16x8 a, bf16x8 b, f32x4 c) {
  return __builtin_amdgcn_mfma_f32_16x16x32_bf16(a, b, c, 0, 0, 0);
}

// ---------------------------------------------------------------------------
// kcellA: grid (8, 32), 448 threads (7 waves).
// Wave w co-tile: w0=i w1=f w2=g w3=o (inputs x,h) ; w4=i' w5=f' w6=g' (x,m).
// ---------------------------------------------------------------------------
__global__ __launch_bounds__(448) void kcellA(
    const unsigned short* __restrict__ in0, long in0bs,
    const unsigned short* __restrict__ hB,
    const unsigned short* __restrict__ memBprev,
    const unsigned short* __restrict__ wfA,
    const float* __restrict__ bA,
    float* __restrict__ C, float* __restrict__ M,
    unsigned short* __restrict__ memBnext,
    float* __restrict__ op)
{
  __shared__ __align__(16) char smem[65536];
  unsigned short* sIn = (unsigned short*)smem;   // 3 inputs x 102 slots x 64ci
  float* sEx = (float*)smem;                     // 7 slabs x 2048 fp32
  unsigned short* sT = (unsigned short*)(smem + 57344);  // 32px x 128ch tile

  const int b = blockIdx.x, r0 = blockIdx.y, tid = threadIdx.x;
  const unsigned short* base0 = in0 + (long)b * in0bs;
  const unsigned short* base1 = hB + ((long)b << 16);
  const unsigned short* base2 = memBprev + ((long)b << 17);

  // stage 3 input row-strips (rows r0-1..r0+1, cols -1..32, 64 ci, swizzled)
  for (int s = tid; s < 3 * 816; s += 448) {
    int inp = s / 816, rem = s - inp * 816;
    int slot = rem >> 3, cg = rem & 7;
    int rr = slot / 34, cl = slot - rr * 34;
    int gr = r0 - 1 + rr, gc = cl - 1;
    uint4 v = make_uint4(0u, 0u, 0u, 0u);
    if ((unsigned)gr < 32u && (unsigned)gc < 32u) {
      if (inp == 0)      v = *(const uint4*)(base0 + ((long)(gr * 32 + gc) << 6) + cg * 8);
      else if (inp == 1) v = *(const uint4*)(base1 + ((long)(gr * 32 + gc) << 6) + cg * 8);
      else               v = *(const uint4*)(base2 + ((long)(gr * 32 + gc) << 7) + 64 + cg * 8);
    }
    *(uint4*)(sIn + inp * 6528 + slot * 64 + ((cg ^ (slot & 7)) * 8)) = v;
  }
  __syncthreads();

  const int w = tid >> 6, lane = tid & 63, q = lane >> 4, n16 = lane & 15;
  f32x4 acc[4][2];
  #pragma unroll
  for (int i = 0; i < 4; ++i) { acc[i][0] = (f32x4){0,0,0,0}; acc[i][1] = (f32x4){0,0,0,0}; }

  const unsigned short* sb1 = sIn + ((w < 4) ? 6528 : 13056);
  const unsigned short* wbase = wfA + (long)w * 73728;

  #pragma unroll
  for (int p = 0; p < 2; ++p) {
    const unsigned short* sb = p ? sb1 : sIn;
    #pragma unroll
    for (int tap = 0; tap < 9; ++tap) {
      const int dy = tap / 3, dx = tap - dy * 3;
      #pragma unroll
      for (int cc = 0; cc < 2; ++cc) {
        const unsigned short* wp = wbase + (long)(((p * 9 + tap) * 2 + cc) * 4) * 512 + lane * 8;
        bf16x8 a0 = *(const bf16x8*)(wp);
        bf16x8 a1 = *(const bf16x8*)(wp + 512);
        bf16x8 a2 = *(const bf16x8*)(wp + 1024);
        bf16x8 a3 = *(const bf16x8*)(wp + 1536);
        const int g = cc * 4 + q;
        bf16x8 bf0, bf1;
        { int slot = dy * 34 + n16 + dx;
          bf0 = *(const bf16x8*)(sb + slot * 64 + ((g ^ (slot & 7)) * 8)); }
        { int slot = dy * 34 + 16 + n16 + dx;
          bf1 = *(const bf16x8*)(sb + slot * 64 + ((g ^ (slot & 7)) * 8)); }
        acc[0][0] = mfma16(a0, bf0, acc[0][0]); acc[0][1] = mfma16(a0, bf1, acc[0][1]);
        acc[1][0] = mfma16(a1, bf0, acc[1][0]); acc[1][1] = mfma16(a1, bf1, acc[1][1]);
        acc[2][0] = mfma16(a2, bf0, acc[2][0]); acc[2][1] = mfma16(a2, bf1, acc[2][1]);
        acc[3][0] = mfma16(a3, bf0, acc[3][0]); acc[3][1] = mfma16(a3, bf1, acc[3][1]);
      }
    }
  }

  __syncthreads();   // all waves done reading sIn before slab overwrite

  // hoist epilogue C/M loads (independent of sEx) above exchange barriers;
  // statically indexed (rule: runtime-indexed arrays go to scratch)
  float cPre[5], mPre[5];
  #pragma unroll
  for (int k = 0; k < 5; ++k) {
    const int idx = tid + k * 448;
    if (idx < 2048) {
      const int ch = idx >> 5, pxl = idx & 31;
      const long cmo = ((long)b * 64 + ch) * 1024 + r0 * 32 + pxl;
      cPre[k] = C[cmo];
      mPre[k] = M[cmo];
    }
  }

  #pragma unroll
  for (int i = 0; i < 4; ++i)
    #pragma unroll
    for (int j = 0; j < 2; ++j)
      #pragma unroll
      for (int r = 0; r < 4; ++r)
        sEx[w * 2048 + (i * 16 + q * 4 + r) * 32 + (j * 16 + n16)] = acc[i][j][r];
  __syncthreads();

  // gate1 epilogue: state update + bf16 tile in LDS
  #pragma unroll
  for (int k = 0; k < 5; ++k) {
    const int idx = tid + k * 448;
    if (idx < 2048) {
      const int ch = idx >> 5, pxl = idx & 31;
      const int pxg = r0 * 32 + pxl;
      float iv = sEx[idx]         + bA[ch];
      float fv = sEx[2048 + idx]  + bA[64 + ch];
      float gv = sEx[4096 + idx]  + bA[128 + ch];
      float ov = sEx[6144 + idx]  + bA[192 + ch];
      float i2 = sEx[8192 + idx]  + bA[256 + ch];
      float f2 = sEx[10240 + idx] + bA[320 + ch];
      float g2 = sEx[12288 + idx] + bA[384 + ch];
      const long cmo = ((long)b * 64 + ch) * 1024 + pxg;
      float cn = sigf(fv) * cPre[k] + sigf(iv) * tanhfast(gv);
      float mn = sigf(f2) * mPre[k] + sigf(i2) * tanhfast(g2);
      C[cmo] = cn; M[cmo] = mn; op[cmo] = ov;
      sT[pxl * 128 + (((ch >> 3) ^ (pxl & 7)) * 8) + (ch & 7)] = f2b(cn);
      const int chm = 64 + ch;
      sT[pxl * 128 + (((chm >> 3) ^ (pxl & 7)) * 8) + (chm & 7)] = f2b(mn);
    }
  }
  __syncthreads();

  // coalesced flush: 512 uint4 (32px x 16 ch-groups)
  for (int u = tid; u < 512; u += 448) {
    const int px = u >> 4, cg = u & 15;
    uint4 v = *(const uint4*)(sT + px * 128 + ((cg ^ (px & 7)) * 8));
    *(uint4*)(memBnext + (((long)b * 1024 + r0 * 32 + px) << 7) + cg * 8) = v;
  }
}

// ---------------------------------------------------------------------------
// kcellB: grid (8, 32), 512 threads (8 waves). 40 K-steps (36 convO + 4 convL)
// split 5/wave; LDS reduce; gate2 epilogue; op loads hoisted.
// ---------------------------------------------------------------------------
__global__ __launch_bounds__(512) void kcellB(
    const unsigned short* __restrict__ memB,
    const unsigned short* __restrict__ wfBl,
    const float* __restrict__ op, const float* __restrict__ bl,
    unsigned short* __restrict__ hBw, unsigned short* __restrict__ outsBt,
    int writeOuts)
{
  __shared__ __align__(16) char smem[77824];
  unsigned short* sIn = (unsigned short*)smem;   // 102 slots x 128 ci
  float* sEx = (float*)smem;                     // 9 slabs x 2048 fp32
  unsigned short* sT = (unsigned short*)(smem + 73728);  // 32px x 64ch tile

  const int b = blockIdx.x, r0 = blockIdx.y, tid = threadIdx.x;
  const unsigned short* bp = memB + ((long)b << 17);
  for (int s = tid; s < 102 * 16; s += 512) {
    int slot = s >> 4, cg = s & 15;
    int rr = slot / 34, cl = slot - rr * 34;
    int gr = r0 - 1 + rr, gc = cl - 1;
    uint4 v = make_uint4(0u, 0u, 0u, 0u);
    if ((unsigned)gr < 32u && (unsigned)gc < 32u)
      v = *(const uint4*)(bp + ((long)(gr * 32 + gc) << 7) + cg * 8);
    *(uint4*)(sIn + slot * 128 + ((cg ^ (slot & 7)) * 8)) = v;
  }
  __syncthreads();

  const int w = tid >> 6, lane = tid & 63, q = lane >> 4, n16 = lane & 15;
  f32x4 accO[4][2], accL[4][2];
  #pragma unroll
  for (int f = 0; f < 4; ++f) {
    accO[f][0] = (f32x4){0.f,0.f,0.f,0.f}; accO[f][1] = (f32x4){0.f,0.f,0.f,0.f};
    accL[f][0] = (f32x4){0.f,0.f,0.f,0.f}; accL[f][1] = (f32x4){0.f,0.f,0.f,0.f};
  }

  #pragma unroll
  for (int s5 = 0; s5 < 5; ++s5) {
    const int s = w * 5 + s5;
    const bool isL = (s >= 36);
    const int tap = isL ? 4 : (s >> 2);
    const int cc  = isL ? (s - 36) : (s & 3);
    const int dy = tap / 3, dx = tap - dy * 3;
    const unsigned short* wp = wfBl + (long)s * 2048 + lane * 8;
    bf16x8 a0 = *(const bf16x8*)(wp);
    bf16x8 a1 = *(const bf16x8*)(wp + 512);
    bf16x8 a2 = *(const bf16x8*)(wp + 1024);
    bf16x8 a3 = *(const bf16x8*)(wp + 1536);
    const int g = cc * 4 + q;
    bf16x8 bf0, bf1;
    { int slot = dy * 34 + n16 + dx;
      bf0 = *(const bf16x8*)(sIn + slot * 128 + ((g ^ (slot & 7)) * 8)); }
    { int slot = dy * 34 + 16 + n16 + dx;
      bf1 = *(const bf16x8*)(sIn + slot * 128 + ((g ^ (slot & 7)) * 8)); }
    if (isL) {
      accL[0][0] = mfma16(a0, bf0, accL[0][0]); accL[0][1] = mfma16(a0, bf1, accL[0][1]);
      accL[1][0] = mfma16(a1, bf0, accL[1][0]); accL[1][1] = mfma16(a1, bf1, accL[1][1]);
      accL[2][0] = mfma16(a2, bf0, accL[2][0]); accL[2][1] = mfma16(a2, bf1, accL[2][1]);
      accL[3][0] = mfma16(a3, bf0, accL[3][0]); accL[3][1] = mfma16(a3, bf1, accL[3][1]);
    } else {
      accO[0][0] = mfma16(a0, bf0, accO[0][0]); accO[0][1] = mfma16(a0, bf1, accO[0][1]);
      accO[1][0] = mfma16(a1, bf0, accO[1][0]); accO[1][1] = mfma16(a1, bf1, accO[1][1]);
      accO[2][0] = mfma16(a2, bf0, accO[2][0]); accO[2][1] = mfma16(a2, bf1, accO[2][1]);
      accO[3][0] = mfma16(a3, bf0, accO[3][0]); accO[3][1] = mfma16(a3, bf1, accO[3][1]);
    }
  }

  // hoist epilogue op loads (independent of sEx) above exchange barrier
  float oPre[4];
  #pragma unroll
  for (int k = 0; k < 4; ++k) {
    const int idx = tid + k * 512;
    const int ch = idx >> 5, pxl = idx & 31;
    oPre[k] = op[((long)b * 64 + ch) * 1024 + r0 * 32 + pxl];
  }

  __syncthreads();
  #pragma unroll
  for (int i = 0; i < 4; ++i)
    #pragma unroll
    for (int j = 0; j < 2; ++j)
      #pragma unroll
      for (int r = 0; r < 4; ++r)
        sEx[w * 2048 + (i * 16 + q * 4 + r) * 32 + (j * 16 + n16)] = accO[i][j][r];
  if (w == 7) {
    #pragma unroll
    for (int i = 0; i < 4; ++i)
      #pragma unroll
      for (int j = 0; j < 2; ++j)
        #pragma unroll
        for (int r = 0; r < 4; ++r)
          sEx[16384 + (i * 16 + q * 4 + r) * 32 + (j * 16 + n16)] = accL[i][j][r];
  }
  __syncthreads();

  #pragma unroll
  for (int k = 0; k < 4; ++k) {
    const int idx = tid + k * 512;
    const int ch = idx >> 5, pxl = idx & 31;
    float o = oPre[k];
    #pragma unroll
    for (int ww = 0; ww < 8; ++ww) o += sEx[ww * 2048 + idx];
    float l = sEx[16384 + idx] + bl[ch];
    sT[pxl * 64 + (((ch >> 3) ^ (pxl & 7)) * 8) + (ch & 7)] = f2b(sigf(o) * tanhfast(l));
  }
  __syncthreads();

  for (int u = tid; u < 256; u += 512) {
    const int px = u >> 3, cg = u & 7;
    uint4 v = *(const uint4*)(sT + px * 64 + ((cg ^ (px & 7)) * 8));
    const long base = (((long)b * 1024 + r0 * 32 + px) << 6) + cg * 8;
    *(uint4*)(hBw + base) = v;
    if (writeOuts) *(uint4*)(outsBt + base) = v;
  }
}

// ---------------------------------------------------------------------------
// Final conv machinery (verbatim R2/R3, proven correct)
// ---------------------------------------------------------------------------
__device__ __forceinline__ void conv3_acc(
    const unsigned short* __restrict__ ip, int ciStride, int ciOff,
    const unsigned short* __restrict__ wf, int ncc, int ccoff,
    unsigned short* sIn, f32x4 (&acc)[4][4])
{
  const int tid = threadIdx.x;
  const int r0  = (int)blockIdx.y * 8;
  for (int s = tid; s < 2720; s += 256) {
    int slot = s >> 3, cg = s & 7;
    int rr = slot / 34, cl = slot - rr * 34;
    int gr = r0 - 1 + rr, gc = cl - 1;
    uint4 v = make_uint4(0u, 0u, 0u, 0u);
    if ((unsigned)gr < 32u && (unsigned)gc < 32u)
      v = *(const uint4*)(ip + (long)(gr * 32 + gc) * ciStride + ciOff + cg * 8);
    *(uint4*)(sIn + slot * 64 + ((cg ^ (slot & 7)) * 8)) = v;
  }
  __syncthreads();
  const int lane = tid & 63, w = tid >> 6;
  const int q = lane >> 4, n16 = lane & 15;
  #pragma unroll
  for (int i = 0; i < 4; ++i)
    #pragma unroll
    for (int j = 0; j < 4; ++j)
      acc[i][j] = (f32x4){0.f, 0.f, 0.f, 0.f};
  #pragma unroll
  for (int tap = 0; tap < 9; ++tap) {
    const int dy = tap / 3, dx = tap - dy * 3;
    #pragma unroll
    for (int cc = 0; cc < 2; ++cc) {
      const unsigned short* wp = wf + (long)(tap * ncc + ccoff + cc) * 2048 + lane * 8;
      bf16x8 a0 = *(const bf16x8*)(wp);
      bf16x8 a1 = *(const bf16x8*)(wp + 512);
      bf16x8 a2 = *(const bf16x8*)(wp + 1024);
      bf16x8 a3 = *(const bf16x8*)(wp + 1536);
      const int cs = cc * 4 + q;
      bf16x8 bfr[4];
      #pragma unroll
      for (int pf = 0; pf < 4; ++pf) {
        int slot = (w * 2 + (pf >> 1) + dy) * 34 + (pf & 1) * 16 + dx + n16;
        bfr[pf] = *(const bf16x8*)(sIn + slot * 64 + ((cs ^ (slot & 7)) * 8));
      }
      #pragma unroll
      for (int j = 0; j < 4; ++j) {
        acc[0][j] = mfma16(a0, bfr[j], acc[0][j]);
        acc[1][j] = mfma16(a1, bfr[j], acc[1][j]);
        acc[2][j] = mfma16(a2, bfr[j], acc[2][j]);
        acc[3][j] = mfma16(a3, bfr[j], acc[3][j]);
      }
    }
  }
}

__global__ __launch_bounds__(256) void kconv_final(
    const unsigned short* __restrict__ outsB,
    const unsigned short* __restrict__ wdf, const float* __restrict__ bd,
    float* __restrict__ dout)
{
  __shared__ __align__(16) unsigned short sIn[21760];
  const int img = blockIdx.x;
  const int b = img / 19, t = img - b * 19;
  f32x4 acc[4][4];
  conv3_acc(outsB + ((long)t * 8 + b) * 65536, 64, 0, wdf, 2, 0, sIn, acc);
  const int tid = threadIdx.x;
  const int lane = tid & 63, w = tid >> 6;
  const int q = lane >> 4, n16 = lane & 15;
  const int r0 = (int)blockIdx.y * 8;
  float* ob = dout + (long)img * 65536;
  #pragma unroll
  for (int i = 0; i < 4; ++i) {
    #pragma unroll
    for (int r = 0; r < 4; ++r) {
      const int co = i * 16 + q * 4 + r;
      const float bv = bd[co];
      #pragma unroll
      for (int j = 0; j < 4; ++j) {
        int row = r0 + w * 2 + (j >> 1);
        int col = (j & 1) * 16 + n16;
        ob[((co >> 3) * 32 + row) * 256 + (co & 7) * 32 + col] = sigf(acc[i][j][r] + bv);
      }
    }
  }
}

// patch division -> bf16 channels-last [b*10+t][1024][64]; grid (80, 32)
__global__ __launch_bounds__(256) void kpatch(const float* __restrict__ x,
                                              unsigned short* __restrict__ xpB)
{
  __shared__ __align__(16) unsigned short sT[2048];
  const int img = blockIdx.x, p = blockIdx.y, tid = threadIdx.x;
  const float* xi = x + (long)img * 65536;
  unsigned short* xo = xpB + (long)img * 65536;
  int ch = tid >> 2, q0 = (tid & 3) * 8;
  const float* s = xi + ((ch >> 3) * 32 + p) * 256 + (ch & 7) * 32 + q0;
  float4 v0 = *(const float4*)s, v1 = *(const float4*)(s + 4);
  float vv[8] = {v0.x, v0.y, v0.z, v0.w, v1.x, v1.y, v1.z, v1.w};
  #pragma unroll
  for (int k = 0; k < 8; ++k) {
    int qq = q0 + k;
    sT[qq * 64 + (((ch >> 3) ^ (qq & 7)) * 8) + (ch & 7)] = f2b(vv[k]);
  }
  __syncthreads();
  int qr = tid >> 3, cg = tid & 7;
  uint4 v = *(const uint4*)(sT + qr * 64 + ((cg ^ (qr & 7)) * 8));
  *(uint4*)(xo + (long)(p * 32 + qr) * 64 + cg * 8) = v;
}

// weight fragment packer (used for Wd only)
__global__ __launch_bounds__(256) void kprepw(const float* __restrict__ src,
                                              unsigned short* __restrict__ dst,
                                              int Cout, int Cin, int KK)
{
  long n = (long)Cout * Cin * KK;
  long idx = (long)blockIdx.x * 256 + threadIdx.x;
  if (idx >= n) return;
  int ncc = Cin >> 5;
  long tmp = idx >> 3; int e = (int)(idx & 7);
  int lane = (int)(tmp & 63); tmp >>= 6;
  int cf = (int)(tmp & 3); tmp >>= 2;
  int cc = (int)(tmp % ncc); tmp /= ncc;
  int tap = (int)(tmp % KK); int chunk = (int)(tmp / KK);
  int co = chunk * 64 + cf * 16 + (lane & 15);
  int ci = cc * 32 + (lane >> 4) * 8 + e;
  dst[idx] = f2b(src[((long)co * Cin + ci) * KK + tap]);
}

// pack fused stage-1 weights (R3 layout): [l][w][p][tap][cc][frag][lane][8]
__global__ __launch_bounds__(256) void kpackA(
    const float* __restrict__ Wx, const float* __restrict__ Wh,
    const float* __restrict__ Wm, unsigned short* __restrict__ wfA)
{
  long idx = (long)blockIdx.x * 256 + threadIdx.x;
  if (idx >= 2064384) return;
  int e = (int)(idx & 7);
  long t = idx >> 3;
  int lane = (int)(t & 63); t >>= 6;
  int frag = (int)(t & 3);  t >>= 2;
  int cc   = (int)(t & 1);  t >>= 1;
  int tap  = (int)(t % 9);  t /= 9;
  int p    = (int)(t & 1);  t >>= 1;
  int w    = (int)(t % 7);
  int l    = (int)(t / 7);
  int co = frag * 16 + (lane & 15);
  int ci = cc * 32 + (lane >> 4) * 8 + e;
  const float* src; int row;
  if (w < 4) {
    if (p == 0) { src = Wx + (long)l * 258048; row = (w == 3 ? 384 : w * 64) + co; }
    else        { src = Wh + (long)l * 147456; row = (w == 3 ? 192 : w * 64) + co; }
  } else {
    if (p == 0) { src = Wx + (long)l * 258048; row = 192 + (w - 4) * 64 + co; }
    else        { src = Wm + (long)l * 110592; row = (w - 4) * 64 + co; }
  }
  wfA[idx] = f2b(src[((long)row * 64 + ci) * 9 + tap]);
}

// pack convO/convL step-ordered weights (R3 layout): [l][s 0..39][frag][lane][8]
__global__ __launch_bounds__(256) void kpackB(
    const float* __restrict__ Wo, const float* __restrict__ Wl,
    unsigned short* __restrict__ wfB)
{
  long idx = (long)blockIdx.x * 256 + threadIdx.x;
  if (idx >= 327680) return;
  int e = (int)(idx & 7);
  long t = idx >> 3;
  int lane = (int)(t & 63); t >>= 6;
  int frag = (int)(t & 3);  t >>= 2;
  int s    = (int)(t % 40);
  int l    = (int)(t / 40);
  int co = frag * 16 + (lane & 15);
  float v;
  if (s < 36) {
    int tap = s >> 2, cc = s & 3;
    int ci = cc * 32 + (lane >> 4) * 8 + e;
    v = Wo[(long)l * 73728 + ((long)co * 128 + ci) * 9 + tap];
  } else {
    int cc = s - 36;
    int ci = cc * 32 + (lane >> 4) * 8 + e;
    v = Wl[(long)l * 8192 + (long)co * 128 + ci];
  }
  wfB[idx] = f2b(v);
}

// pre-summed gate biases: [l][slot i,f,g,o(+bo),i2,f2,g2][64]
__global__ __launch_bounds__(256) void kpackbA(
    const float* __restrict__ bx, const float* __restrict__ bh,
    const float* __restrict__ bm, const float* __restrict__ bo,
    float* __restrict__ bA)
{
  int idx = blockIdx.x * 256 + threadIdx.x;
  if (idx >= 1792) return;
  int ch = idx & 63, w = (idx >> 6) % 7, l = (idx >> 6) / 7;
  const float* bxl = bx + l * 448;
  const float* bhl = bh + l * 256;
  const float* bml = bm + l * 192;
  const float* bol = bo + l * 64;
  float v;
  if (w < 3)       v = bxl[w * 64 + ch] + bhl[w * 64 + ch];
  else if (w == 3) v = bxl[384 + ch] + bhl[192 + ch] + bol[ch];
  else             v = bxl[192 + (w - 4) * 64 + ch] + bml[(w - 4) * 64 + ch];
  bA[idx] = v;
}

extern "C" void kernel_launch(void* const* d_in, const int* in_sizes, int n_in,
                              void* d_out, int out_size, void* d_ws, size_t ws_size,
                              hipStream_t stream)
{
  (void)in_sizes; (void)n_in; (void)out_size;
  if (ws_size < WS_NEEDED_FLOATS * sizeof(float)) return;

  const float* x  = (const float*)d_in[0];
  const float* Wx = (const float*)d_in[3];
  const float* bx = (const float*)d_in[4];
  const float* Wh = (const float*)d_in[5];
  const float* bh = (const float*)d_in[6];
  const float* Wm = (const float*)d_in[7];
  const float* bm = (const float*)d_in[8];
  const float* Wo = (const float*)d_in[9];
  const float* bo = (const float*)d_in[10];
  const float* Wl = (const float*)d_in[11];
  const float* bl = (const float*)d_in[12];
  const float* Wd = (const float*)d_in[13];
  const float* bd = (const float*)d_in[14];
  float* ws  = (float*)d_ws;
  float* out = (float*)d_out;

  unsigned short* xpB   = (unsigned short*)(ws + OFF_XPB);
  unsigned short* outsB = (unsigned short*)(ws + OFF_OUTSB);
  unsigned short* hB    = (unsigned short*)(ws + OFF_HB);
  float*          C     = ws + OFF_C;
  float*          M     = ws + OFF_M;
  unsigned short* memB0 = (unsigned short*)(ws + OFF_MEMB);
  unsigned short* memB1 = memB0 + 1048576;
  float*          OP    = ws + OFF_OP;
  unsigned short* wfA   = (unsigned short*)(ws + OFF_WFA);
  unsigned short* wfB   = (unsigned short*)(ws + OFF_WFB);
  unsigned short* wfD   = (unsigned short*)(ws + OFF_WFD);
  float*          bA    = ws + OFF_BA;

  kpackA<<<dim3(8064), 256, 0, stream>>>(Wx, Wh, Wm, wfA);
  kpackB<<<dim3(1280), 256, 0, stream>>>(Wo, Wl, wfB);
  kpackbA<<<dim3(7), 256, 0, stream>>>(bx, bh, bm, bo, bA);
  kprepw<<<dim3(144), 256, 0, stream>>>(Wd, wfD, 64, 64, 9);
  kpatch<<<dim3(80, 32), 256, 0, stream>>>(x, xpB);
  // zero hB, C, M, memB(2x), OP (contiguous region)
  hipMemsetAsync(ws + OFF_HB, 0, (OFF_WFA - OFF_HB) * sizeof(float), stream);

  for (int t = 0; t < T; ++t) {
    for (int l = 0; l < 4; ++l) {
      const int cell = t * 4 + l;
      const unsigned short* in0; long ibs;
      if (l == 0) {
        if (t < INLEN) { in0 = xpB + (long)t * 65536; ibs = 655360; }
        else           { in0 = outsB + (long)(t - 1) * 524288; ibs = 65536; }
      } else {
        in0 = hB + (long)(l - 1) * 524288; ibs = 65536;
      }
      const unsigned short* mprev = (cell & 1) ? memB1 : memB0;
      unsigned short*       mnext = (cell & 1) ? memB0 : memB1;
      kcellA<<<dim3(8, 32), 448, 0, stream>>>(
          in0, ibs, hB + (long)l * 524288, mprev,
          wfA + (long)l * 516096, bA + l * 448,
          C + (long)l * 524288, M, mnext, OP);
      kcellB<<<dim3(8, 32), 512, 0, stream>>>(
          mnext, wfB + (long)l * 81920, OP, bl + l * 64,
          hB + (long)l * 524288, outsB + (long)t * 524288, (l == 3) ? 1 : 0);
    }
  }
  kconv_final<<<dim3(152, 4), 256, 0, stream>>>(outsB, wfD, bd, out);
}